// Round 7
// baseline (693.426 us; speedup 1.0000x reference)
//
#include <hip/hip_runtime.h>
#include <hip/hip_bf16.h>

#define KDIM 512
#define NDIM 512
#define ATT  196
#define NB   1024

typedef __attribute__((ext_vector_type(8))) short bf16x8;
typedef __attribute__((ext_vector_type(8))) unsigned short ushort8;
typedef __attribute__((ext_vector_type(4))) float f32x4;

typedef const __attribute__((address_space(1))) unsigned int gas_uint;
typedef __attribute__((address_space(3))) unsigned int las_uint;

__device__ __forceinline__ void gload16(const void* g, void* l) {
    __builtin_amdgcn_global_load_lds((gas_uint*)g, (las_uint*)l, 16, 0, 0);
}

__device__ __forceinline__ float fast_tanh(float x) {
    x = fminf(15.f, fmaxf(-15.f, x));
    float t = __expf(2.f * x);
    return (t - 1.f) / (t + 1.f);
}

__device__ __forceinline__ unsigned short f2bf(float x) {
    union { float f; unsigned u; } v; v.f = x;
    unsigned r = v.u + 0x7FFF + ((v.u >> 16) & 1);   // RNE
    return (unsigned short)(r >> 16);
}

__device__ __forceinline__ unsigned pk2(float a, float b) {
    __hip_bfloat162 h = __float22bfloat162_rn(float2{a, b});
    union { __hip_bfloat162 h2; unsigned u; } c; c.h2 = h;
    return c.u;
}

// ---------------------------------------------------------------------------
// Transpose+cast 6 weights: W[k][n] f32 -> Wt[n][k] bf16 ([n][k] row-major).
// ---------------------------------------------------------------------------
__global__ __launch_bounds__(256) void prep_weights(
        const float* __restrict__ W0, const float* __restrict__ W1,
        const float* __restrict__ W2, const float* __restrict__ W3,
        const float* __restrict__ W4, const float* __restrict__ W5,
        unsigned short* __restrict__ Wt) {
    int w = blockIdx.x >> 6;
    int t = blockIdx.x & 63;
    int k0 = (t >> 3) << 6, n0 = (t & 7) << 6;
    const float* W = (w == 0) ? W0 : (w == 1) ? W1 : (w == 2) ? W2 :
                     (w == 3) ? W3 : (w == 4) ? W4 : W5;
    __shared__ float tile[64][65];
    int tid = threadIdx.x;
    int nc = tid & 15, kr = tid >> 4;
#pragma unroll
    for (int i = 0; i < 4; ++i) {
        int k = kr + i * 16;
        float4 v = *(const float4*)&W[(size_t)(k0 + k) * NDIM + n0 + nc * 4];
        tile[k][nc * 4 + 0] = v.x; tile[k][nc * 4 + 1] = v.y;
        tile[k][nc * 4 + 2] = v.z; tile[k][nc * 4 + 3] = v.w;
    }
    __syncthreads();
    int n = tid >> 2, ks = tid & 3;
    ushort8 v0, v1;
#pragma unroll
    for (int j = 0; j < 8; ++j) v0[j] = f2bf(tile[ks * 16 + j][n]);
#pragma unroll
    for (int j = 0; j < 8; ++j) v1[j] = f2bf(tile[ks * 16 + 8 + j][n]);
    size_t base = ((size_t)w << 18) + (size_t)(n0 + n) * KDIM + k0 + ks * 16;
    *(ushort8*)&Wt[base] = v0;
    *(ushort8*)&Wt[base + 8] = v1;
}

// ---------------------------------------------------------------------------
// Small GEMM: out = act(A[1024,512] @ Wt^T + bias). BM=64, BN=128,
// 256 thr = 4 waves (2Mx2N), wave 32x64. Two ops batched via blockIdx.y.
// act: 0=relu 1=tanh 2=none
// ---------------------------------------------------------------------------
__global__ __launch_bounds__(256) void gemm64(
        const float* __restrict__ A0, const unsigned short* __restrict__ W0,
        const float* __restrict__ bia0, float* __restrict__ O0, int act0,
        const float* __restrict__ A1, const unsigned short* __restrict__ W1,
        const float* __restrict__ bia1, float* __restrict__ O1, int act1) {
    const int op = blockIdx.y;
    const float* A = op ? A1 : A0;
    const unsigned short* Bt = op ? W1 : W0;
    const float* bias = op ? bia1 : bia0;
    float* out = op ? O1 : O0;
    const int act = op ? act1 : act0;

    __shared__ unsigned short A_lds[2][64 * 32];
    __shared__ unsigned short B_lds[2][128 * 32];

    const int tid = threadIdx.x;
    const int gm0 = (blockIdx.x >> 2) * 64, gn0 = (blockIdx.x & 3) * 128;
    const int wid = tid >> 6, lane = tid & 63;
    const int wm = wid >> 1, wn = wid & 1;
    const int lr = lane & 15, lk = lane >> 4;

    const int arow = tid >> 2, akc = tid & 3;
    const float* aptr = A + (size_t)(gm0 + arow) * KDIM + akc * 8;
    const int aoff = arow * 32 + ((akc ^ ((arow >> 1) & 3)) << 3);

    auto stageB = [&](int kt, int buf) {
#pragma unroll
        for (int j = 0; j < 2; ++j) {
            int c = tid + j * 256;
            int col = c >> 2, slot = c & 3;
            const unsigned short* src = Bt + (size_t)(gn0 + col) * KDIM +
                                        ((slot ^ ((col >> 1) & 3)) << 3) + kt * 32;
            gload16(src, &B_lds[buf][c * 8]);
        }
    };

    f32x4 acc[2][4] = {};

    {
        float4 x0 = *(const float4*)aptr;
        float4 x1 = *(const float4*)(aptr + 4);
        stageB(0, 0);
        uint4 p;
        p.x = pk2(x0.x, x0.y); p.y = pk2(x0.z, x0.w);
        p.z = pk2(x1.x, x1.y); p.w = pk2(x1.z, x1.w);
        *(uint4*)&A_lds[0][aoff] = p;
    }
    __syncthreads();

    const int swk = ((lk ^ ((lr >> 1) & 3)) << 3);
    for (int kt = 0; kt < 16; ++kt) {
        const int buf = kt & 1;
        float4 x0, x1;
        if (kt < 15) {
            const float* ap = aptr + (kt + 1) * 32;
            x0 = *(const float4*)ap;
            x1 = *(const float4*)(ap + 4);
            stageB(kt + 1, buf ^ 1);
        }
        bf16x8 af[2], bfr[4];
#pragma unroll
        for (int m = 0; m < 2; ++m)
            af[m] = *(const bf16x8*)&A_lds[buf][(wm * 32 + m * 16 + lr) * 32 + swk];
#pragma unroll
        for (int n = 0; n < 4; ++n)
            bfr[n] = *(const bf16x8*)&B_lds[buf][(wn * 64 + n * 16 + lr) * 32 + swk];
#pragma unroll
        for (int m = 0; m < 2; ++m)
#pragma unroll
            for (int n = 0; n < 4; ++n)
                acc[m][n] = __builtin_amdgcn_mfma_f32_16x16x32_bf16(af[m], bfr[n], acc[m][n], 0, 0, 0);
        if (kt < 15) {
            uint4 p;
            p.x = pk2(x0.x, x0.y); p.y = pk2(x0.z, x0.w);
            p.z = pk2(x1.x, x1.y); p.w = pk2(x1.z, x1.w);
            *(uint4*)&A_lds[buf ^ 1][aoff] = p;
        }
        __syncthreads();
    }

#pragma unroll
    for (int m = 0; m < 2; ++m)
#pragma unroll
        for (int n = 0; n < 4; ++n) {
            int col = gn0 + wn * 64 + n * 16 + lr;
            float bsv = bias[col];
#pragma unroll
            for (int r = 0; r < 4; ++r) {
                int row = gm0 + wm * 32 + m * 16 + lk * 4 + r;
                float v = acc[m][n][r] + bsv;
                if (act == 0) v = fmaxf(v, 0.f);
                else if (act == 1) v = fast_tanh(v);
                out[(size_t)row * NDIM + col] = v;
            }
        }
}

// ---------------------------------------------------------------------------
// Score GEMM, R7: persistent-B design.
// Block owns 128 N-cols; B slice (128x512 bf16 = 128KB) loaded to LDS ONCE.
// Then 4 M-tiles x 16 K-steps = 64-step pipeline; per step only A staged
// (8KB: f32->reg (issued 2 steps ahead) -> cvt_pk -> ds_write, 2-buffer).
// Barriers are lgkm-only (vmcnt NOT drained -> A prefetch stays in flight).
// Per-mtile epilogue: score partials + atomicAdd.
// Grid 1568 = 8 XCD x 49 groups x 4 nblk (N-siblings adjacent per XCD).
// ---------------------------------------------------------------------------
__launch_bounds__(256, 1)
__global__ void gemm_score(const float* __restrict__ A,
                           const unsigned short* __restrict__ Bt,
                           const float* __restrict__ b_ctx,
                           const float* __restrict__ h_emb,
                           const float* __restrict__ Walpha,
                           float* __restrict__ score) {
    __shared__ unsigned short B_res[16 * 4096];    // 131072 B: [kt][col][slot]
    __shared__ unsigned short A_buf[2][128 * 32];  // 16384 B
    __shared__ float s_red[2][128];                // 1024 B

    const int tid = threadIdx.x;
    const int bid = blockIdx.x;
    const int xcd = bid & 7, v = bid >> 3;
    const int nblk = v & 3, gl = v >> 2;
    const int group = xcd * 49 + gl;               // 0..391
    const int gbase = group * 512;                 // first A row of this block
    const int gn0 = nblk * 128;

    const int wid = tid >> 6, lane = tid & 63;
    const int wm = wid >> 1, wn = wid & 1;
    const int lr = lane & 15, lk = lane >> 4;
    const int swk = ((lk ^ ((lr >> 1) & 3)) << 3);

    // A staging mapping: row=tid>>1, k-half=tid&1 (16 f32 -> 2 swizzled slots)
    const int arow = tid >> 1, ahalf = tid & 1;
    const int skc0 = (ahalf * 2) ^ ((arow >> 1) & 3);
    const int aoff0 = arow * 32 + skc0 * 8;
    const int aoff1 = arow * 32 + (skc0 ^ 1) * 8;

    // ---- per-lane epilogue constants (drained before manual-count region) ----
    int cols[4];
    float wav[4], bcv[4];
#pragma unroll
    for (int n = 0; n < 4; ++n) {
        cols[n] = gn0 + wn * 64 + n * 16 + lr;
        wav[n] = Walpha[cols[n]];
        bcv[n] = b_ctx[cols[n]];
    }
    asm volatile("s_waitcnt vmcnt(0)" ::: "memory");
    __builtin_amdgcn_sched_barrier(0);

    // ---- B preload: 8192 x 16B chunks, 32 per thread ----
#pragma unroll
    for (int i = 0; i < 32; ++i) {
        int c = tid + i * 256;
        int kt = c >> 9, w = c & 511;
        int col = w >> 2, slot = w & 3;
        int kc = slot ^ ((col >> 1) & 3);
        gload16(Bt + (size_t)(gn0 + col) * KDIM + kt * 32 + kc * 8, &B_res[c * 8]);
    }
    __builtin_amdgcn_sched_barrier(0);

    f32x4 acc[4][4] = {};
    float4 xe0, xe1, xe2, xe3, xo0, xo1, xo2, xo3;

    auto LOADA = [&](int s, float4& y0, float4& y1, float4& y2, float4& y3) {
        const float* ap = A + (size_t)(gbase + ((s >> 4) << 7) + arow) * KDIM +
                          ((s & 15) << 5) + ahalf * 16;
        y0 = *(const float4*)(ap);
        y1 = *(const float4*)(ap + 4);
        y2 = *(const float4*)(ap + 8);
        y3 = *(const float4*)(ap + 12);
    };
    auto CVTW = [&](const float4& y0, const float4& y1, const float4& y2,
                    const float4& y3, int buf) {
        uint4 p0, p1;
        p0.x = pk2(y0.x, y0.y); p0.y = pk2(y0.z, y0.w);
        p0.z = pk2(y1.x, y1.y); p0.w = pk2(y1.z, y1.w);
        p1.x = pk2(y2.x, y2.y); p1.y = pk2(y2.z, y2.w);
        p1.z = pk2(y3.x, y3.y); p1.w = pk2(y3.z, y3.w);
        *(uint4*)&A_buf[buf][aoff0] = p0;
        *(uint4*)&A_buf[buf][aoff1] = p1;
    };
    auto STEP = [&](int bufA, int kt) {
        bf16x8 af[4], bfr[4];
        const unsigned short* bb = &B_res[kt * 4096];
#pragma unroll
        for (int n = 0; n < 4; ++n)
            bfr[n] = *(const bf16x8*)&bb[(wn * 64 + n * 16 + lr) * 32 + swk];
#pragma unroll
        for (int m = 0; m < 4; ++m)
            af[m] = *(const bf16x8*)&A_buf[bufA][(wm * 64 + m * 16 + lr) * 32 + swk];
#pragma unroll
        for (int m = 0; m < 4; ++m)
#pragma unroll
            for (int n = 0; n < 4; ++n)
                acc[m][n] = __builtin_amdgcn_mfma_f32_16x16x32_bf16(af[m], bfr[n], acc[m][n], 0, 0, 0);
    };
    auto BAR = [&]() {
        asm volatile("s_waitcnt lgkmcnt(0)" ::: "memory");
        __builtin_amdgcn_sched_barrier(0);
        __builtin_amdgcn_s_barrier();
        __builtin_amdgcn_sched_barrier(0);
    };
    auto EPILOGUE = [&](int mt) {
        const int r0 = gbase + (mt << 7);
        const int bb0 = r0 / ATT;
        const int bsplit = (bb0 + 1) * ATT;
        const int bb1 = (bb0 < NB - 1) ? bb0 + 1 : bb0;
        float ch0[4], ch1[4];
#pragma unroll
        for (int n = 0; n < 4; ++n) {
            ch0[n] = h_emb[(size_t)bb0 * NDIM + cols[n]] + bcv[n];
            ch1[n] = h_emb[(size_t)bb1 * NDIM + cols[n]] + bcv[n];
        }
#pragma unroll
        for (int m = 0; m < 4; ++m) {
#pragma unroll
            for (int r = 0; r < 4; ++r) {
                const int rloc = wm * 64 + m * 16 + lk * 4 + r;
                const int rg = r0 + rloc;
                const bool hi = (rg >= bsplit);
                float sum = 0.f;
#pragma unroll
                for (int n = 0; n < 4; ++n)
                    sum += fast_tanh(acc[m][n][r] + (hi ? ch1[n] : ch0[n])) * wav[n];
                sum += __shfl_xor(sum, 1);
                sum += __shfl_xor(sum, 2);
                sum += __shfl_xor(sum, 4);
                sum += __shfl_xor(sum, 8);
                if (lr == 0) s_red[wn][rloc] = sum;
            }
        }
        BAR();
        if (tid < 128) {
            float tot = s_red[0][tid] + s_red[1][tid];
            int rg = r0 + tid;
            int bb = (rg >= bsplit) ? bb1 : bb0;
            atomicAdd(&score[(size_t)bb * 197 + (rg - bb * ATT) + 1], tot);
        }
        BAR();
#pragma unroll
        for (int m = 0; m < 4; ++m)
#pragma unroll
            for (int n = 0; n < 4; ++n)
                acc[m][n] = (f32x4){0.f, 0.f, 0.f, 0.f};
    };

    // ---- prologue: A0 staged (its auto-wait also drains B preload), A1 in flight ----
    LOADA(0, xe0, xe1, xe2, xe3);
    LOADA(1, xo0, xo1, xo2, xo3);
    __builtin_amdgcn_sched_barrier(0);
    CVTW(xe0, xe1, xe2, xe3, 0);    // compiler waits A0 -> drains all older (B) too
    BAR();

    // ---- main loop: 64 steps (4 mtiles x 16 kt), unroll-2 for reg sets ----
#pragma unroll 1
    for (int i = 0; i < 32; ++i) {
        // even step s=2i: reads buf0
        if (i < 31) LOADA(2 * i + 2, xe0, xe1, xe2, xe3);
        __builtin_amdgcn_sched_barrier(0);
        STEP(0, (2 * i) & 15);
        CVTW(xo0, xo1, xo2, xo3, 1);            // consumes loads(2i+1)
        BAR();
        // odd step s=2i+1: reads buf1
        if (i < 31) LOADA(2 * i + 3, xo0, xo1, xo2, xo3);
        __builtin_amdgcn_sched_barrier(0);
        STEP(1, (2 * i + 1) & 15);
        if (i < 31) CVTW(xe0, xe1, xe2, xe3, 0); // consumes loads(2i+2)
        BAR();
        if ((i & 7) == 7) EPILOGUE(i >> 3);
    }
}

// ---------------------------------------------------------------------------
// Per-batch: sentinel score (pos 0) from sent_emb+h_emb, softmax over 197,
// atten_out[b,:] = al0*sent_lin + sum_s al[s+1]*att[b,s,:] + h_lin
// ---------------------------------------------------------------------------
__global__ __launch_bounds__(256) void softmax_chat(
        const float* __restrict__ score, const float* __restrict__ sent_emb,
        const float* __restrict__ h_emb, const float* __restrict__ Walpha,
        const float* __restrict__ sent_lin, const float* __restrict__ h_lin,
        const float* __restrict__ att, float* __restrict__ atten_out) {
    int b = blockIdx.x, tid = threadIdx.x;
    __shared__ float al[200];
    __shared__ float r4[4];

    float2 se = ((const float2*)(sent_emb + (size_t)b * NDIM))[tid];
    float2 he = ((const float2*)(h_emb + (size_t)b * NDIM))[tid];
    float2 wa = ((const float2*)Walpha)[tid];
    float val = fast_tanh(se.x + he.x) * wa.x + fast_tanh(se.y + he.y) * wa.y;
#pragma unroll
    for (int o = 32; o; o >>= 1) val += __shfl_xor(val, o);
    if ((tid & 63) == 0) r4[tid >> 6] = val;
    __syncthreads();
    float ssent = r4[0] + r4[1] + r4[2] + r4[3];
    __syncthreads();

    float v = -1e30f;
    if (tid < 197) v = (tid == 0) ? ssent : score[(size_t)b * 197 + tid];
    float m = v;
#pragma unroll
    for (int o = 32; o; o >>= 1) m = fmaxf(m, __shfl_xor(m, o));
    if ((tid & 63) == 0) r4[tid >> 6] = m;
    __syncthreads();
    m = fmaxf(fmaxf(r4[0], r4[1]), fmaxf(r4[2], r4[3]));
    __syncthreads();
    float e = (tid < 197) ? __expf(v - m) : 0.f;
    float s = e;
#pragma unroll
    for (int o = 32; o; o >>= 1) s += __shfl_xor(s, o);
    if ((tid & 63) == 0) r4[tid >> 6] = s;
    __syncthreads();
    s = r4[0] + r4[1] + r4[2] + r4[3];
    if (tid < 197) al[tid] = e / s;
    __syncthreads();

    const float2* af = (const float2*)(att + (size_t)b * ATT * KDIM);
    float2 a0 = ((const float2*)(sent_lin + (size_t)b * KDIM))[tid];
    float w0 = al[0];
    float2 accv; accv.x = w0 * a0.x; accv.y = w0 * a0.y;
#pragma unroll 14
    for (int ss = 0; ss < ATT; ++ss) {
        float w = al[ss + 1];
        float2 x = af[(size_t)ss * 256 + tid];
        accv.x += w * x.x; accv.y += w * x.y;
    }
    float2 hl = ((const float2*)(h_lin + (size_t)b * KDIM))[tid];
    accv.x += hl.x; accv.y += hl.y;
    ((float2*)(atten_out + (size_t)b * KDIM))[tid] = accv;
}

// ---------------------------------------------------------------------------
extern "C" void kernel_launch(void* const* d_in, const int* in_sizes, int n_in,
                              void* d_out, int out_size, void* d_ws, size_t ws_size,
                              hipStream_t stream) {
    const float* h     = (const float*)d_in[0];
    const float* sent  = (const float*)d_in[1];
    const float* att   = (const float*)d_in[2];
    const float* W_ctx = (const float*)d_in[3];
    const float* b_ctx = (const float*)d_in[4];
    const float* W_sl  = (const float*)d_in[5];
    const float* b_sl  = (const float*)d_in[6];
    const float* W_se  = (const float*)d_in[7];
    const float* b_se  = (const float*)d_in[8];
    const float* W_hl  = (const float*)d_in[9];
    const float* b_hl  = (const float*)d_in[10];
    const float* W_he  = (const float*)d_in[11];
    const float* b_he  = (const float*)d_in[12];
    const float* W_al  = (const float*)d_in[13];
    // d_in[14] = b_alpha: constant across positions, cancels in softmax
    const float* W_a2h = (const float*)d_in[15];
    const float* b_a2h = (const float*)d_in[16];
    float* out = (float*)d_out;

    char* ws = (char*)d_ws;
    unsigned short* Wt = (unsigned short*)ws;                 // 6 * 512KB bf16 = 3MB
    float* sent_lin = (float*)(ws + 6u * 512 * 1024);
    float* h_lin    = sent_lin + (size_t)NB * 512;
    float* h_emb    = h_lin    + (size_t)NB * 512;
    float* sent_emb = h_emb    + (size_t)NB * 512;
    float* scorebuf = sent_emb + (size_t)NB * 512;            // 1024*197
    float* atten    = scorebuf + (size_t)NB * 197;

    const size_t WSZ = 512 * 512;  // ushorts per weight
    // Wt order: 0=W_sl 1=W_hl 2=W_he 3=W_ctx 4=W_a2h 5=W_se
    prep_weights<<<384, 256, 0, stream>>>(W_sl, W_hl, W_he, W_ctx, W_a2h, W_se, Wt);
    hipMemsetAsync(scorebuf, 0, (size_t)NB * 197 * sizeof(float), stream);

    // sent_lin = relu(sent@W_sl+b_sl); h_lin = tanh(h@W_hl+b_hl)
    gemm64<<<dim3(64, 2), 256, 0, stream>>>(
        sent, Wt + 0 * WSZ, b_sl, sent_lin, 0,
        h,    Wt + 1 * WSZ, b_hl, h_lin,    1);
    // h_emb = h_lin@W_he+b_he; sent_emb = sent_lin@W_se+b_se
    gemm64<<<dim3(64, 2), 256, 0, stream>>>(
        h_lin,    Wt + 2 * WSZ, b_he, h_emb,    2,
        sent_lin, Wt + 5 * WSZ, b_se, sent_emb, 2);

    // visual scores -> scorebuf[b*197 + 1 + s]
    gemm_score<<<1568, 256, 0, stream>>>(att, Wt + 3 * WSZ, b_ctx, h_emb, W_al, scorebuf);

    softmax_chat<<<NB, 256, 0, stream>>>(scorebuf, sent_emb, h_emb, W_al,
                                         sent_lin, h_lin, att, atten);

    // out = tanh(atten@W_a2h + b_a2h)
    gemm64<<<dim3(64, 1), 256, 0, stream>>>(
        atten, Wt + 4 * WSZ, b_a2h, out, 1,
        atten, Wt + 4 * WSZ, b_a2h, out, 1);
}

// Round 8
// 375.032 us; speedup vs baseline: 1.8490x; 1.8490x over previous
//
#include <hip/hip_runtime.h>
#include <hip/hip_bf16.h>

#define KDIM 512
#define NDIM 512
#define ATT  196
#define NB   1024

typedef __attribute__((ext_vector_type(8))) short bf16x8;
typedef __attribute__((ext_vector_type(8))) unsigned short ushort8;
typedef __attribute__((ext_vector_type(4))) float f32x4;

typedef const __attribute__((address_space(1))) unsigned int gas_uint;
typedef __attribute__((address_space(3))) unsigned int las_uint;

__device__ __forceinline__ void gload16(const void* g, void* l) {
    __builtin_amdgcn_global_load_lds((gas_uint*)g, (las_uint*)l, 16, 0, 0);
}

__device__ __forceinline__ float fast_tanh(float x) {
    x = fminf(15.f, fmaxf(-15.f, x));
    float t = __expf(2.f * x);
    return (t - 1.f) / (t + 1.f);
}

__device__ __forceinline__ unsigned short f2bf(float x) {
    union { float f; unsigned u; } v; v.f = x;
    unsigned r = v.u + 0x7FFF + ((v.u >> 16) & 1);   // RNE
    return (unsigned short)(r >> 16);
}

__device__ __forceinline__ unsigned pk2(float a, float b) {
    __hip_bfloat162 h = __float22bfloat162_rn(float2{a, b});
    union { __hip_bfloat162 h2; unsigned u; } c; c.h2 = h;
    return c.u;
}

// ---------------------------------------------------------------------------
// Transpose+cast 6 weights: W[k][n] f32 -> Wt[n][k] bf16 ([n][k] row-major).
// ---------------------------------------------------------------------------
__global__ __launch_bounds__(256) void prep_weights(
        const float* __restrict__ W0, const float* __restrict__ W1,
        const float* __restrict__ W2, const float* __restrict__ W3,
        const float* __restrict__ W4, const float* __restrict__ W5,
        unsigned short* __restrict__ Wt) {
    int w = blockIdx.x >> 6;
    int t = blockIdx.x & 63;
    int k0 = (t >> 3) << 6, n0 = (t & 7) << 6;
    const float* W = (w == 0) ? W0 : (w == 1) ? W1 : (w == 2) ? W2 :
                     (w == 3) ? W3 : (w == 4) ? W4 : W5;
    __shared__ float tile[64][65];
    int tid = threadIdx.x;
    int nc = tid & 15, kr = tid >> 4;
#pragma unroll
    for (int i = 0; i < 4; ++i) {
        int k = kr + i * 16;
        float4 v = *(const float4*)&W[(size_t)(k0 + k) * NDIM + n0 + nc * 4];
        tile[k][nc * 4 + 0] = v.x; tile[k][nc * 4 + 1] = v.y;
        tile[k][nc * 4 + 2] = v.z; tile[k][nc * 4 + 3] = v.w;
    }
    __syncthreads();
    int n = tid >> 2, ks = tid & 3;
    ushort8 v0, v1;
#pragma unroll
    for (int j = 0; j < 8; ++j) v0[j] = f2bf(tile[ks * 16 + j][n]);
#pragma unroll
    for (int j = 0; j < 8; ++j) v1[j] = f2bf(tile[ks * 16 + 8 + j][n]);
    size_t base = ((size_t)w << 18) + (size_t)(n0 + n) * KDIM + k0 + ks * 16;
    *(ushort8*)&Wt[base] = v0;
    *(ushort8*)&Wt[base + 8] = v1;
}

// ---------------------------------------------------------------------------
// Small GEMM: out = act(A[1024,512] @ Wt^T + bias). BM=64, BN=128,
// 256 thr = 4 waves (2Mx2N), wave 32x64. Two ops batched via blockIdx.y.
// act: 0=relu 1=tanh 2=none
// ---------------------------------------------------------------------------
__global__ __launch_bounds__(256) void gemm64(
        const float* __restrict__ A0, const unsigned short* __restrict__ W0,
        const float* __restrict__ bia0, float* __restrict__ O0, int act0,
        const float* __restrict__ A1, const unsigned short* __restrict__ W1,
        const float* __restrict__ bia1, float* __restrict__ O1, int act1) {
    const int op = blockIdx.y;
    const float* A = op ? A1 : A0;
    const unsigned short* Bt = op ? W1 : W0;
    const float* bias = op ? bia1 : bia0;
    float* out = op ? O1 : O0;
    const int act = op ? act1 : act0;

    __shared__ unsigned short A_lds[2][64 * 32];
    __shared__ unsigned short B_lds[2][128 * 32];

    const int tid = threadIdx.x;
    const int gm0 = (blockIdx.x >> 2) * 64, gn0 = (blockIdx.x & 3) * 128;
    const int wid = tid >> 6, lane = tid & 63;
    const int wm = wid >> 1, wn = wid & 1;
    const int lr = lane & 15, lk = lane >> 4;

    const int arow = tid >> 2, akc = tid & 3;
    const float* aptr = A + (size_t)(gm0 + arow) * KDIM + akc * 8;
    const int aoff = arow * 32 + ((akc ^ ((arow >> 1) & 3)) << 3);

    auto stageB = [&](int kt, int buf) {
#pragma unroll
        for (int j = 0; j < 2; ++j) {
            int c = tid + j * 256;
            int col = c >> 2, slot = c & 3;
            const unsigned short* src = Bt + (size_t)(gn0 + col) * KDIM +
                                        ((slot ^ ((col >> 1) & 3)) << 3) + kt * 32;
            gload16(src, &B_lds[buf][c * 8]);
        }
    };

    f32x4 acc[2][4] = {};

    {
        float4 x0 = *(const float4*)aptr;
        float4 x1 = *(const float4*)(aptr + 4);
        stageB(0, 0);
        uint4 p;
        p.x = pk2(x0.x, x0.y); p.y = pk2(x0.z, x0.w);
        p.z = pk2(x1.x, x1.y); p.w = pk2(x1.z, x1.w);
        *(uint4*)&A_lds[0][aoff] = p;
    }
    __syncthreads();

    const int swk = ((lk ^ ((lr >> 1) & 3)) << 3);
    for (int kt = 0; kt < 16; ++kt) {
        const int buf = kt & 1;
        float4 x0, x1;
        if (kt < 15) {
            const float* ap = aptr + (kt + 1) * 32;
            x0 = *(const float4*)ap;
            x1 = *(const float4*)(ap + 4);
            stageB(kt + 1, buf ^ 1);
        }
        bf16x8 af[2], bfr[4];
#pragma unroll
        for (int m = 0; m < 2; ++m)
            af[m] = *(const bf16x8*)&A_lds[buf][(wm * 32 + m * 16 + lr) * 32 + swk];
#pragma unroll
        for (int n = 0; n < 4; ++n)
            bfr[n] = *(const bf16x8*)&B_lds[buf][(wn * 64 + n * 16 + lr) * 32 + swk];
#pragma unroll
        for (int m = 0; m < 2; ++m)
#pragma unroll
            for (int n = 0; n < 4; ++n)
                acc[m][n] = __builtin_amdgcn_mfma_f32_16x16x32_bf16(af[m], bfr[n], acc[m][n], 0, 0, 0);
        if (kt < 15) {
            uint4 p;
            p.x = pk2(x0.x, x0.y); p.y = pk2(x0.z, x0.w);
            p.z = pk2(x1.x, x1.y); p.w = pk2(x1.z, x1.w);
            *(uint4*)&A_lds[buf ^ 1][aoff] = p;
        }
        __syncthreads();
    }

#pragma unroll
    for (int m = 0; m < 2; ++m)
#pragma unroll
        for (int n = 0; n < 4; ++n) {
            int col = gn0 + wn * 64 + n * 16 + lr;
            float bsv = bias[col];
#pragma unroll
            for (int r = 0; r < 4; ++r) {
                int row = gm0 + wm * 32 + m * 16 + lk * 4 + r;
                float v = acc[m][n][r] + bsv;
                if (act == 0) v = fmaxf(v, 0.f);
                else if (act == 1) v = fast_tanh(v);
                out[(size_t)row * NDIM + col] = v;
            }
        }
}

// ---------------------------------------------------------------------------
// Score GEMM, R8: ALL staging via global_load_lds (m97 op structure).
// A staged as f32 into LDS (source-swizzled granules: g ^= row&7), converted
// to bf16 at the consumer (ds_read_b128 f32 x2 + cvt_pk x4 per frag).
// No reg-staged loads, no ds_write, no manual vmcnt: plain 2-buffer loop
// with __syncthreads. BM=BN=128, BK=32, 256 thr (2Mx2N waves, 64x64/wave).
// LDS 49KB -> 3 blocks/CU. Epilogue: per-row partial of
// sum_col tanh(acc + b_ctx[col] + h_emb[b,col]) * Walpha[col] -> atomicAdd.
// Grid 6272 = 8 XCD x 196 mtiles x 4 nblk (N-siblings adjacent per XCD).
// ---------------------------------------------------------------------------
__launch_bounds__(256, 3)
__global__ void gemm_score(const float* __restrict__ A,
                           const unsigned short* __restrict__ Bt,
                           const float* __restrict__ b_ctx,
                           const float* __restrict__ h_emb,
                           const float* __restrict__ Walpha,
                           float* __restrict__ score) {
    __shared__ float A_f[2][128 * 32];             // 2 x 16 KB (f32, swizzled granules)
    __shared__ unsigned short B_lds[2][128 * 32];  // 2 x 8 KB
    __shared__ float ch_s[2][128];
    __shared__ float wa_s[128];
    __shared__ float s_red[2][128];

    const int tid  = threadIdx.x;
    const int bidx = blockIdx.x;
    const int xcd  = bidx & 7, u = bidx >> 3;
    const int mblk = xcd * 196 + (u >> 2), nblk = u & 3;
    const int gm0  = mblk * 128, gn0 = nblk * 128;

    const int wid = tid >> 6, lane = tid & 63;
    const int wm  = wid >> 1, wn = wid & 1;
    const int lr  = lane & 15, lk = lane >> 4;

    const int bb0 = gm0 / ATT;
    {
        int j = tid >> 7, cloc = tid & 127;
        int bb = bb0 + j; if (bb > NB - 1) bb = NB - 1;
        ch_s[j][cloc] = b_ctx[gn0 + cloc] + h_emb[(size_t)bb * NDIM + gn0 + cloc];
        if (tid < 128) wa_s[tid] = Walpha[gn0 + tid];
    }

    // A staging: granule c (16B of f32) -> row=c>>3, dest slot g=c&7 holds
    // source granule g^(row&7). 4 gload_lds per thread, LDS dest linear.
    const float* asrc[4];
#pragma unroll
    for (int i = 0; i < 4; ++i) {
        int c = tid + i * 256;
        int row = c >> 3, g = c & 7;
        int srcg = g ^ (row & 7);
        asrc[i] = A + (size_t)(gm0 + row) * KDIM + srcg * 4;
    }
    auto stageA = [&](int kt, int buf) {
#pragma unroll
        for (int i = 0; i < 4; ++i)
            gload16(asrc[i] + kt * 32, &A_f[buf][(tid + i * 256) * 4]);
    };

    // B staging: chunk c -> col=c>>2, slot=c&3 holds src kc=slot^((col>>1)&3)
    const int c1 = tid + 256;
    const int bcol0 = tid >> 2, bk0 = (tid & 3) ^ ((bcol0 >> 1) & 3);
    const int bcol1 = c1 >> 2,  bk1 = (c1 & 3) ^ ((bcol1 >> 1) & 3);
    const unsigned short* bsrc0 = Bt + (size_t)(gn0 + bcol0) * KDIM + bk0 * 8;
    const unsigned short* bsrc1 = Bt + (size_t)(gn0 + bcol1) * KDIM + bk1 * 8;
    auto stageB = [&](int kt, int buf) {
        gload16(bsrc0 + kt * 32, &B_lds[buf][tid * 8]);
        gload16(bsrc1 + kt * 32, &B_lds[buf][c1 * 8]);
    };

    f32x4 acc[4][4] = {};
    const int swk = ((lk ^ ((lr >> 1) & 3)) << 3);

    // A frag read constants: row = wm*64 + m*16 + lr; slots lk*2^(row&7), +^1
    const int arw = ((wm * 64 + lr) & 7);          // (m*16) doesn't affect row&7
    const int as0 = (lk * 2) ^ arw;
    const int as1 = (lk * 2 + 1) ^ arw;

    stageA(0, 0);
    stageB(0, 0);
    __syncthreads();

#pragma unroll 1
    for (int kt = 0; kt < 16; ++kt) {
        const int buf = kt & 1;
        if (kt < 15) {
            stageA(kt + 1, buf ^ 1);
            stageB(kt + 1, buf ^ 1);
        }
        bf16x8 af[4], bfr[4];
#pragma unroll
        for (int n = 0; n < 4; ++n)
            bfr[n] = *(const bf16x8*)&B_lds[buf][(wn * 64 + n * 16 + lr) * 32 + swk];
#pragma unroll
        for (int m = 0; m < 4; ++m) {
            const int rbase = (wm * 64 + m * 16 + lr) * 32;
            float4 fa = *(const float4*)&A_f[buf][rbase + as0 * 4];
            float4 fb = *(const float4*)&A_f[buf][rbase + as1 * 4];
            uint4 p;
            p.x = pk2(fa.x, fa.y); p.y = pk2(fa.z, fa.w);
            p.z = pk2(fb.x, fb.y); p.w = pk2(fb.z, fb.w);
            union { uint4 u; bf16x8 v; } cc; cc.u = p;
            af[m] = cc.v;
        }
#pragma unroll
        for (int m = 0; m < 4; ++m)
#pragma unroll
            for (int n = 0; n < 4; ++n)
                acc[m][n] = __builtin_amdgcn_mfma_f32_16x16x32_bf16(af[m], bfr[n], acc[m][n], 0, 0, 0);
        __syncthreads();
    }

    // ---- epilogue: per-row partial score ----
    const int bsplit = (bb0 + 1) * ATT;
#pragma unroll
    for (int m = 0; m < 4; ++m) {
#pragma unroll
        for (int r = 0; r < 4; ++r) {
            int rloc = wm * 64 + m * 16 + lk * 4 + r;
            int rg = gm0 + rloc;
            int sel = (rg >= bsplit) ? 1 : 0;
            float sum = 0.f;
#pragma unroll
            for (int n = 0; n < 4; ++n) {
                int cloc = wn * 64 + n * 16 + lr;
                sum += fast_tanh(acc[m][n][r] + ch_s[sel][cloc]) * wa_s[cloc];
            }
            sum += __shfl_xor(sum, 1);
            sum += __shfl_xor(sum, 2);
            sum += __shfl_xor(sum, 4);
            sum += __shfl_xor(sum, 8);
            if (lr == 0) s_red[wn][rloc] = sum;
        }
    }
    __syncthreads();
    if (tid < 128) {
        float tot = s_red[0][tid] + s_red[1][tid];
        int rg = gm0 + tid;
        int sel = (rg >= bsplit) ? 1 : 0;
        int bb = bb0 + sel;
        atomicAdd(&score[(size_t)bb * 197 + (rg - bb * ATT) + 1], tot);
    }
}

// ---------------------------------------------------------------------------
// Per-batch: sentinel score (pos 0) from sent_emb+h_emb, softmax over 197,
// atten_out[b,:] = al0*sent_lin + sum_s al[s+1]*att[b,s,:] + h_lin
// ---------------------------------------------------------------------------
__global__ __launch_bounds__(256) void softmax_chat(
        const float* __restrict__ score, const float* __restrict__ sent_emb,
        const float* __restrict__ h_emb, const float* __restrict__ Walpha,
        const float* __restrict__ sent_lin, const float* __restrict__ h_lin,
        const float* __restrict__ att, float* __restrict__ atten_out) {
    int b = blockIdx.x, tid = threadIdx.x;
    __shared__ float al[200];
    __shared__ float r4[4];

    float2 se = ((const float2*)(sent_emb + (size_t)b * NDIM))[tid];
    float2 he = ((const float2*)(h_emb + (size_t)b * NDIM))[tid];
    float2 wa = ((const float2*)Walpha)[tid];
    float val = fast_tanh(se.x + he.x) * wa.x + fast_tanh(se.y + he.y) * wa.y;
#pragma unroll
    for (int o = 32; o; o >>= 1) val += __shfl_xor(val, o);
    if ((tid & 63) == 0) r4[tid >> 6] = val;
    __syncthreads();
    float ssent = r4[0] + r4[1] + r4[2] + r4[3];
    __syncthreads();

    float v = -1e30f;
    if (tid < 197) v = (tid == 0) ? ssent : score[(size_t)b * 197 + tid];
    float m = v;
#pragma unroll
    for (int o = 32; o; o >>= 1) m = fmaxf(m, __shfl_xor(m, o));
    if ((tid & 63) == 0) r4[tid >> 6] = m;
    __syncthreads();
    m = fmaxf(fmaxf(r4[0], r4[1]), fmaxf(r4[2], r4[3]));
    __syncthreads();
    float e = (tid < 197) ? __expf(v - m) : 0.f;
    float s = e;
#pragma unroll
    for (int o = 32; o; o >>= 1) s += __shfl_xor(s, o);
    if ((tid & 63) == 0) r4[tid >> 6] = s;
    __syncthreads();
    s = r4[0] + r4[1] + r4[2] + r4[3];
    if (tid < 197) al[tid] = e / s;
    __syncthreads();

    const float2* af = (const float2*)(att + (size_t)b * ATT * KDIM);
    float2 a0 = ((const float2*)(sent_lin + (size_t)b * KDIM))[tid];
    float w0 = al[0];
    float2 accv; accv.x = w0 * a0.x; accv.y = w0 * a0.y;
#pragma unroll 14
    for (int ss = 0; ss < ATT; ++ss) {
        float w = al[ss + 1];
        float2 x = af[(size_t)ss * 256 + tid];
        accv.x += w * x.x; accv.y += w * x.y;
    }
    float2 hl = ((const float2*)(h_lin + (size_t)b * KDIM))[tid];
    accv.x += hl.x; accv.y += hl.y;
    ((float2*)(atten_out + (size_t)b * KDIM))[tid] = accv;
}

// ---------------------------------------------------------------------------
extern "C" void kernel_launch(void* const* d_in, const int* in_sizes, int n_in,
                              void* d_out, int out_size, void* d_ws, size_t ws_size,
                              hipStream_t stream) {
    const float* h     = (const float*)d_in[0];
    const float* sent  = (const float*)d_in[1];
    const float* att   = (const float*)d_in[2];
    const float* W_ctx = (const float*)d_in[3];
    const float* b_ctx = (const float*)d_in[4];
    const float* W_sl  = (const float*)d_in[5];
    const float* b_sl  = (const float*)d_in[6];
    const float* W_se  = (const float*)d_in[7];
    const float* b_se  = (const float*)d_in[8];
    const float* W_hl  = (const float*)d_in[9];
    const float* b_hl  = (const float*)d_in[10];
    const float* W_he  = (const float*)d_in[11];
    const float* b_he  = (const float*)d_in[12];
    const float* W_al  = (const float*)d_in[13];
    // d_in[14] = b_alpha: constant across positions, cancels in softmax
    const float* W_a2h = (const float*)d_in[15];
    const float* b_a2h = (const float*)d_in[16];
    float* out = (float*)d_out;

    char* ws = (char*)d_ws;
    unsigned short* Wt = (unsigned short*)ws;                 // 6 * 512KB bf16 = 3MB
    float* sent_lin = (float*)(ws + 6u * 512 * 1024);
    float* h_lin    = sent_lin + (size_t)NB * 512;
    float* h_emb    = h_lin    + (size_t)NB * 512;
    float* sent_emb = h_emb    + (size_t)NB * 512;
    float* scorebuf = sent_emb + (size_t)NB * 512;            // 1024*197
    float* atten    = scorebuf + (size_t)NB * 197;

    const size_t WSZ = 512 * 512;  // ushorts per weight
    // Wt order: 0=W_sl 1=W_hl 2=W_he 3=W_ctx 4=W_a2h 5=W_se
    prep_weights<<<384, 256, 0, stream>>>(W_sl, W_hl, W_he, W_ctx, W_a2h, W_se, Wt);
    hipMemsetAsync(scorebuf, 0, (size_t)NB * 197 * sizeof(float), stream);

    // sent_lin = relu(sent@W_sl+b_sl); h_lin = tanh(h@W_hl+b_hl)
    gemm64<<<dim3(64, 2), 256, 0, stream>>>(
        sent, Wt + 0 * WSZ, b_sl, sent_lin, 0,
        h,    Wt + 1 * WSZ, b_hl, h_lin,    1);
    // h_emb = h_lin@W_he+b_he; sent_emb = sent_lin@W_se+b_se
    gemm64<<<dim3(64, 2), 256, 0, stream>>>(
        h_lin,    Wt + 2 * WSZ, b_he, h_emb,    2,
        sent_lin, Wt + 5 * WSZ, b_se, sent_emb, 2);

    // visual scores -> scorebuf[b*197 + 1 + s]
    gemm_score<<<6272, 256, 0, stream>>>(att, Wt + 3 * WSZ, b_ctx, h_emb, W_al, scorebuf);

    softmax_chat<<<NB, 256, 0, stream>>>(scorebuf, sent_emb, h_emb, W_al,
                                         sent_lin, h_lin, att, atten);

    // out = tanh(atten@W_a2h + b_a2h)
    gemm64<<<dim3(64, 1), 256, 0, stream>>>(
        atten, Wt + 4 * WSZ, b_a2h, out, 1,
        atten, Wt + 4 * WSZ, b_a2h, out, 1);
}

// Round 9
// 370.051 us; speedup vs baseline: 1.8739x; 1.0135x over previous
//
#include <hip/hip_runtime.h>
#include <hip/hip_bf16.h>

#define KDIM 512
#define NDIM 512
#define ATT  196
#define NB   1024

typedef __attribute__((ext_vector_type(8))) short bf16x8;
typedef __attribute__((ext_vector_type(8))) unsigned short ushort8;
typedef __attribute__((ext_vector_type(4))) float f32x4;

typedef const __attribute__((address_space(1))) unsigned int gas_uint;
typedef __attribute__((address_space(3))) unsigned int las_uint;

__device__ __forceinline__ void gload16(const void* g, void* l) {
    __builtin_amdgcn_global_load_lds((gas_uint*)g, (las_uint*)l, 16, 0, 0);
}

__device__ __forceinline__ float fast_tanh(float x) {
    x = fminf(15.f, fmaxf(-15.f, x));
    float t = __expf(2.f * x);
    return (t - 1.f) / (t + 1.f);
}

__device__ __forceinline__ unsigned short f2bf(float x) {
    union { float f; unsigned u; } v; v.f = x;
    unsigned r = v.u + 0x7FFF + ((v.u >> 16) & 1);   // RNE
    return (unsigned short)(r >> 16);
}

__device__ __forceinline__ unsigned pk2(float a, float b) {
    __hip_bfloat162 h = __float22bfloat162_rn(float2{a, b});
    union { __hip_bfloat162 h2; unsigned u; } c; c.h2 = h;
    return c.u;
}

// ---------------------------------------------------------------------------
// Transpose+cast 6 weights: W[k][n] f32 -> Wt[n][k] bf16 ([n][k] row-major).
// ---------------------------------------------------------------------------
__global__ __launch_bounds__(256) void prep_weights(
        const float* __restrict__ W0, const float* __restrict__ W1,
        const float* __restrict__ W2, const float* __restrict__ W3,
        const float* __restrict__ W4, const float* __restrict__ W5,
        unsigned short* __restrict__ Wt) {
    int w = blockIdx.x >> 6;
    int t = blockIdx.x & 63;
    int k0 = (t >> 3) << 6, n0 = (t & 7) << 6;
    const float* W = (w == 0) ? W0 : (w == 1) ? W1 : (w == 2) ? W2 :
                     (w == 3) ? W3 : (w == 4) ? W4 : W5;
    __shared__ float tile[64][65];
    int tid = threadIdx.x;
    int nc = tid & 15, kr = tid >> 4;
#pragma unroll
    for (int i = 0; i < 4; ++i) {
        int k = kr + i * 16;
        float4 v = *(const float4*)&W[(size_t)(k0 + k) * NDIM + n0 + nc * 4];
        tile[k][nc * 4 + 0] = v.x; tile[k][nc * 4 + 1] = v.y;
        tile[k][nc * 4 + 2] = v.z; tile[k][nc * 4 + 3] = v.w;
    }
    __syncthreads();
    int n = tid >> 2, ks = tid & 3;
    ushort8 v0, v1;
#pragma unroll
    for (int j = 0; j < 8; ++j) v0[j] = f2bf(tile[ks * 16 + j][n]);
#pragma unroll
    for (int j = 0; j < 8; ++j) v1[j] = f2bf(tile[ks * 16 + 8 + j][n]);
    size_t base = ((size_t)w << 18) + (size_t)(n0 + n) * KDIM + k0 + ks * 16;
    *(ushort8*)&Wt[base] = v0;
    *(ushort8*)&Wt[base + 8] = v1;
}

// ---------------------------------------------------------------------------
// Small GEMM: out = act(A[1024,512] @ Wt^T + bias). BM=64, BN=128,
// 256 thr = 4 waves (2Mx2N), wave 32x64. Two ops batched via blockIdx.y.
// act: 0=relu 1=tanh 2=none
// ---------------------------------------------------------------------------
__global__ __launch_bounds__(256) void gemm64(
        const float* __restrict__ A0, const unsigned short* __restrict__ W0,
        const float* __restrict__ bia0, float* __restrict__ O0, int act0,
        const float* __restrict__ A1, const unsigned short* __restrict__ W1,
        const float* __restrict__ bia1, float* __restrict__ O1, int act1) {
    const int op = blockIdx.y;
    const float* A = op ? A1 : A0;
    const unsigned short* Bt = op ? W1 : W0;
    const float* bias = op ? bia1 : bia0;
    float* out = op ? O1 : O0;
    const int act = op ? act1 : act0;

    __shared__ unsigned short A_lds[2][64 * 32];
    __shared__ unsigned short B_lds[2][128 * 32];

    const int tid = threadIdx.x;
    const int gm0 = (blockIdx.x >> 2) * 64, gn0 = (blockIdx.x & 3) * 128;
    const int wid = tid >> 6, lane = tid & 63;
    const int wm = wid >> 1, wn = wid & 1;
    const int lr = lane & 15, lk = lane >> 4;

    const int arow = tid >> 2, akc = tid & 3;
    const float* aptr = A + (size_t)(gm0 + arow) * KDIM + akc * 8;
    const int aoff = arow * 32 + ((akc ^ ((arow >> 1) & 3)) << 3);

    auto stageB = [&](int kt, int buf) {
#pragma unroll
        for (int j = 0; j < 2; ++j) {
            int c = tid + j * 256;
            int col = c >> 2, slot = c & 3;
            const unsigned short* src = Bt + (size_t)(gn0 + col) * KDIM +
                                        ((slot ^ ((col >> 1) & 3)) << 3) + kt * 32;
            gload16(src, &B_lds[buf][c * 8]);
        }
    };

    f32x4 acc[2][4] = {};

    {
        float4 x0 = *(const float4*)aptr;
        float4 x1 = *(const float4*)(aptr + 4);
        stageB(0, 0);
        uint4 p;
        p.x = pk2(x0.x, x0.y); p.y = pk2(x0.z, x0.w);
        p.z = pk2(x1.x, x1.y); p.w = pk2(x1.z, x1.w);
        *(uint4*)&A_lds[0][aoff] = p;
    }
    __syncthreads();

    const int swk = ((lk ^ ((lr >> 1) & 3)) << 3);
    for (int kt = 0; kt < 16; ++kt) {
        const int buf = kt & 1;
        float4 x0, x1;
        if (kt < 15) {
            const float* ap = aptr + (kt + 1) * 32;
            x0 = *(const float4*)ap;
            x1 = *(const float4*)(ap + 4);
            stageB(kt + 1, buf ^ 1);
        }
        bf16x8 af[2], bfr[4];
#pragma unroll
        for (int m = 0; m < 2; ++m)
            af[m] = *(const bf16x8*)&A_lds[buf][(wm * 32 + m * 16 + lr) * 32 + swk];
#pragma unroll
        for (int n = 0; n < 4; ++n)
            bfr[n] = *(const bf16x8*)&B_lds[buf][(wn * 64 + n * 16 + lr) * 32 + swk];
#pragma unroll
        for (int m = 0; m < 2; ++m)
#pragma unroll
            for (int n = 0; n < 4; ++n)
                acc[m][n] = __builtin_amdgcn_mfma_f32_16x16x32_bf16(af[m], bfr[n], acc[m][n], 0, 0, 0);
        if (kt < 15) {
            uint4 p;
            p.x = pk2(x0.x, x0.y); p.y = pk2(x0.z, x0.w);
            p.z = pk2(x1.x, x1.y); p.w = pk2(x1.z, x1.w);
            *(uint4*)&A_lds[buf ^ 1][aoff] = p;
        }
        __syncthreads();
    }

#pragma unroll
    for (int m = 0; m < 2; ++m)
#pragma unroll
        for (int n = 0; n < 4; ++n) {
            int col = gn0 + wn * 64 + n * 16 + lr;
            float bsv = bias[col];
#pragma unroll
            for (int r = 0; r < 4; ++r) {
                int row = gm0 + wm * 32 + m * 16 + lk * 4 + r;
                float v = acc[m][n][r] + bsv;
                if (act == 0) v = fmaxf(v, 0.f);
                else if (act == 1) v = fast_tanh(v);
                out[(size_t)row * NDIM + col] = v;
            }
        }
}

// ---------------------------------------------------------------------------
// Score GEMM, R9: R8 interior scaled to BM=256, BN=128, 512 thr (8 waves,
// 4Mx2N, wave 64x64). A staged f32 via global_load_lds (source-swizzled
// granules g^=(row&7)), consumer-side cvt_pk; B via global_load_lds with
// source-baked swizzle. LDS exactly 80 KB -> 2 blocks/CU (16 waves/CU).
// Per-block fixed costs amortize over 2x MFMA vs R8. Epilogue handles up to
// 3 batch spans (256 rows vs ATT=196). atomicAdd partials into score.
// Grid 3136 = 8 XCD x 98 mtiles x 4 nblk.
// ---------------------------------------------------------------------------
__launch_bounds__(512, 4)
__global__ void gemm_score(const float* __restrict__ A,
                           const unsigned short* __restrict__ Bt,
                           const float* __restrict__ b_ctx,
                           const float* __restrict__ h_emb,
                           const float* __restrict__ Walpha,
                           float* __restrict__ score) {
    __shared__ char smem[81920];
    float (*A_f)[256 * 32] = (float (*)[256 * 32])smem;                       // 2x32KB
    unsigned short (*B_lds)[128 * 32] = (unsigned short (*)[128 * 32])(smem + 65536); // 2x8KB
    // epilogue aliases (A_f region is dead after the K-loop's final barrier)
    float* ch_s = (float*)smem;            // [3][128]
    float* wa_s = (float*)(smem + 1536);   // [128]
    float* s_red = (float*)(smem + 2048);  // [2][256]

    const int tid  = threadIdx.x;
    const int bidx = blockIdx.x;
    const int xcd  = bidx & 7, u = bidx >> 3;
    const int mblk = xcd * 98 + (u >> 2), nblk = u & 3;
    const int gm0  = mblk * 256, gn0 = nblk * 128;

    const int wid = tid >> 6, lane = tid & 63;
    const int wm  = wid >> 1, wn = wid & 1;
    const int lr  = lane & 15, lk = lane >> 4;

    // A staging: granule c (16B f32) -> row=c>>3, dest slot g=c&7 holds
    // source granule g^(row&7). 4 gload_lds/thread, LDS dest linear.
    const float* asrc[4];
#pragma unroll
    for (int i = 0; i < 4; ++i) {
        int c = tid + i * 512;
        int row = c >> 3, g = c & 7;
        asrc[i] = A + (size_t)(gm0 + row) * KDIM + ((g ^ (row & 7)) << 2);
    }
    auto stageA = [&](int kt, int buf) {
#pragma unroll
        for (int i = 0; i < 4; ++i)
            gload16(asrc[i] + kt * 32, &A_f[buf][(tid + i * 512) * 4]);
    };

    // B staging: chunk c=tid -> col=c>>2, slot=c&3 holds src kc=slot^((col>>1)&3)
    const int bcol = tid >> 2, bslot = tid & 3;
    const unsigned short* bsrc = Bt + (size_t)(gn0 + bcol) * KDIM +
                                 ((bslot ^ ((bcol >> 1) & 3)) << 3);
    auto stageB = [&](int kt, int buf) {
        gload16(bsrc + kt * 32, &B_lds[buf][tid * 8]);
    };

    f32x4 acc[4][4] = {};
    const int swk = ((lk ^ ((lr >> 1) & 3)) << 3);
    const int arw = lr & 7;                 // row&7 for frag rows (wm*64,m*16 = 0 mod 8)
    const int as0 = (lk * 2) ^ arw;
    const int as1 = (lk * 2 + 1) ^ arw;

    stageA(0, 0);
    stageB(0, 0);
    __syncthreads();

#pragma unroll 1
    for (int kt = 0; kt < 16; ++kt) {
        const int buf = kt & 1;
        if (kt < 15) {
            stageA(kt + 1, buf ^ 1);
            stageB(kt + 1, buf ^ 1);
        }
        bf16x8 af[4], bfr[4];
#pragma unroll
        for (int n = 0; n < 4; ++n)
            bfr[n] = *(const bf16x8*)&B_lds[buf][(wn * 64 + n * 16 + lr) * 32 + swk];
#pragma unroll
        for (int m = 0; m < 4; ++m) {
            const int rbase = (wm * 64 + m * 16 + lr) * 32;
            float4 fa = *(const float4*)&A_f[buf][rbase + as0 * 4];
            float4 fb = *(const float4*)&A_f[buf][rbase + as1 * 4];
            uint4 p;
            p.x = pk2(fa.x, fa.y); p.y = pk2(fa.z, fa.w);
            p.z = pk2(fb.x, fb.y); p.w = pk2(fb.z, fb.w);
            union { uint4 u; bf16x8 v; } cc; cc.u = p;
            af[m] = cc.v;
        }
#pragma unroll
        for (int m = 0; m < 4; ++m)
#pragma unroll
            for (int n = 0; n < 4; ++n)
                acc[m][n] = __builtin_amdgcn_mfma_f32_16x16x32_bf16(af[m], bfr[n], acc[m][n], 0, 0, 0);
        __syncthreads();
    }

    // ---- epilogue (A_f/B_lds dead; aliased buffers live now) ----
    const int bb0 = gm0 / ATT;
    {
        int j = tid >> 7;                   // 0..3
        int c = tid & 127;
        if (j < 3) {
            int bb = bb0 + j; if (bb > NB - 1) bb = NB - 1;
            ch_s[j * 128 + c] = b_ctx[gn0 + c] + h_emb[(size_t)bb * NDIM + gn0 + c];
        }
        if (tid < 128) wa_s[tid] = Walpha[gn0 + tid];
    }
    __syncthreads();

#pragma unroll
    for (int m = 0; m < 4; ++m) {
#pragma unroll
        for (int r = 0; r < 4; ++r) {
            int rloc = wm * 64 + m * 16 + lk * 4 + r;     // 0..255
            int rg = gm0 + rloc;
            int sel = rg / ATT - bb0;                     // 0..2
            float sum = 0.f;
#pragma unroll
            for (int n = 0; n < 4; ++n) {
                int cloc = wn * 64 + n * 16 + lr;
                sum += fast_tanh(acc[m][n][r] + ch_s[sel * 128 + cloc]) * wa_s[cloc];
            }
            sum += __shfl_xor(sum, 1);
            sum += __shfl_xor(sum, 2);
            sum += __shfl_xor(sum, 4);
            sum += __shfl_xor(sum, 8);
            if (lr == 0) s_red[wn * 256 + rloc] = sum;
        }
    }
    __syncthreads();
    if (tid < 256) {
        float tot = s_red[tid] + s_red[256 + tid];
        int rg = gm0 + tid;
        int bb = rg / ATT;
        atomicAdd(&score[(size_t)bb * 197 + (rg - bb * ATT) + 1], tot);
    }
}

// ---------------------------------------------------------------------------
// Per-batch: sentinel score (pos 0) from sent_emb+h_emb, softmax over 197,
// atten_out[b,:] = al0*sent_lin + sum_s al[s+1]*att[b,s,:] + h_lin
// ---------------------------------------------------------------------------
__global__ __launch_bounds__(256) void softmax_chat(
        const float* __restrict__ score, const float* __restrict__ sent_emb,
        const float* __restrict__ h_emb, const float* __restrict__ Walpha,
        const float* __restrict__ sent_lin, const float* __restrict__ h_lin,
        const float* __restrict__ att, float* __restrict__ atten_out) {
    int b = blockIdx.x, tid = threadIdx.x;
    __shared__ float al[200];
    __shared__ float r4[4];

    float2 se = ((const float2*)(sent_emb + (size_t)b * NDIM))[tid];
    float2 he = ((const float2*)(h_emb + (size_t)b * NDIM))[tid];
    float2 wa = ((const float2*)Walpha)[tid];
    float val = fast_tanh(se.x + he.x) * wa.x + fast_tanh(se.y + he.y) * wa.y;
#pragma unroll
    for (int o = 32; o; o >>= 1) val += __shfl_xor(val, o);
    if ((tid & 63) == 0) r4[tid >> 6] = val;
    __syncthreads();
    float ssent = r4[0] + r4[1] + r4[2] + r4[3];
    __syncthreads();

    float v = -1e30f;
    if (tid < 197) v = (tid == 0) ? ssent : score[(size_t)b * 197 + tid];
    float m = v;
#pragma unroll
    for (int o = 32; o; o >>= 1) m = fmaxf(m, __shfl_xor(m, o));
    if ((tid & 63) == 0) r4[tid >> 6] = m;
    __syncthreads();
    m = fmaxf(fmaxf(r4[0], r4[1]), fmaxf(r4[2], r4[3]));
    __syncthreads();
    float e = (tid < 197) ? __expf(v - m) : 0.f;
    float s = e;
#pragma unroll
    for (int o = 32; o; o >>= 1) s += __shfl_xor(s, o);
    if ((tid & 63) == 0) r4[tid >> 6] = s;
    __syncthreads();
    s = r4[0] + r4[1] + r4[2] + r4[3];
    if (tid < 197) al[tid] = e / s;
    __syncthreads();

    const float2* af = (const float2*)(att + (size_t)b * ATT * KDIM);
    float2 a0 = ((const float2*)(sent_lin + (size_t)b * KDIM))[tid];
    float w0 = al[0];
    float2 accv; accv.x = w0 * a0.x; accv.y = w0 * a0.y;
#pragma unroll 14
    for (int ss = 0; ss < ATT; ++ss) {
        float w = al[ss + 1];
        float2 x = af[(size_t)ss * 256 + tid];
        accv.x += w * x.x; accv.y += w * x.y;
    }
    float2 hl = ((const float2*)(h_lin + (size_t)b * KDIM))[tid];
    accv.x += hl.x; accv.y += hl.y;
    ((float2*)(atten_out + (size_t)b * KDIM))[tid] = accv;
}

// ---------------------------------------------------------------------------
extern "C" void kernel_launch(void* const* d_in, const int* in_sizes, int n_in,
                              void* d_out, int out_size, void* d_ws, size_t ws_size,
                              hipStream_t stream) {
    const float* h     = (const float*)d_in[0];
    const float* sent  = (const float*)d_in[1];
    const float* att   = (const float*)d_in[2];
    const float* W_ctx = (const float*)d_in[3];
    const float* b_ctx = (const float*)d_in[4];
    const float* W_sl  = (const float*)d_in[5];
    const float* b_sl  = (const float*)d_in[6];
    const float* W_se  = (const float*)d_in[7];
    const float* b_se  = (const float*)d_in[8];
    const float* W_hl  = (const float*)d_in[9];
    const float* b_hl  = (const float*)d_in[10];
    const float* W_he  = (const float*)d_in[11];
    const float* b_he  = (const float*)d_in[12];
    const float* W_al  = (const float*)d_in[13];
    // d_in[14] = b_alpha: constant across positions, cancels in softmax
    const float* W_a2h = (const float*)d_in[15];
    const float* b_a2h = (const float*)d_in[16];
    float* out = (float*)d_out;

    char* ws = (char*)d_ws;
    unsigned short* Wt = (unsigned short*)ws;                 // 6 * 512KB bf16 = 3MB
    float* sent_lin = (float*)(ws + 6u * 512 * 1024);
    float* h_lin    = sent_lin + (size_t)NB * 512;
    float* h_emb    = h_lin    + (size_t)NB * 512;
    float* sent_emb = h_emb    + (size_t)NB * 512;
    float* scorebuf = sent_emb + (size_t)NB * 512;            // 1024*197
    float* atten    = scorebuf + (size_t)NB * 197;

    const size_t WSZ = 512 * 512;  // ushorts per weight
    // Wt order: 0=W_sl 1=W_hl 2=W_he 3=W_ctx 4=W_a2h 5=W_se
    prep_weights<<<384, 256, 0, stream>>>(W_sl, W_hl, W_he, W_ctx, W_a2h, W_se, Wt);
    hipMemsetAsync(scorebuf, 0, (size_t)NB * 197 * sizeof(float), stream);

    // sent_lin = relu(sent@W_sl+b_sl); h_lin = tanh(h@W_hl+b_hl)
    gemm64<<<dim3(64, 2), 256, 0, stream>>>(
        sent, Wt + 0 * WSZ, b_sl, sent_lin, 0,
        h,    Wt + 1 * WSZ, b_hl, h_lin,    1);
    // h_emb = h_lin@W_he+b_he; sent_emb = sent_lin@W_se+b_se
    gemm64<<<dim3(64, 2), 256, 0, stream>>>(
        h_lin,    Wt + 2 * WSZ, b_he, h_emb,    2,
        sent_lin, Wt + 5 * WSZ, b_se, sent_emb, 2);

    // visual scores -> scorebuf[b*197 + 1 + s]
    gemm_score<<<3136, 512, 0, stream>>>(att, Wt + 3 * WSZ, b_ctx, h_emb, W_al, scorebuf);

    softmax_chat<<<NB, 256, 0, stream>>>(scorebuf, sent_emb, h_emb, W_al,
                                         sent_lin, h_lin, att, atten);

    // out = tanh(atten@W_a2h + b_a2h)
    gemm64<<<dim3(64, 1), 256, 0, stream>>>(
        atten, Wt + 4 * WSZ, b_a2h, out, 1,
        atten, Wt + 4 * WSZ, b_a2h, out, 1);
}